// Round 2
// baseline (246.724 us; speedup 1.0000x reference)
//
#include <hip/hip_runtime.h>
#include <math.h>

#define BB 64
#define SS 1024
#define VV 1024
#define DD 512

__device__ __forceinline__ float gelu_tanh(float x) {
    // jax.nn.gelu approximate=True (flax default)
    const float k = 0.7978845608028654f; // sqrt(2/pi)
    float x3 = x * x * x;
    return 0.5f * x * (1.0f + tanhf(k * (x + 0.044715f * x3)));
}

// One block per (batch, head). head 0 = map MLP, head 1 = step MLP.
// 256 threads/block; each thread computes 2 hidden units of the D=512 GEMV.
__global__ void __launch_bounds__(256)
gate_scatter_kernel(
    const float* __restrict__ evidence,             // [B,D]
    const int* __restrict__ marker_id,              // [B]
    const int* __restrict__ source_idx,             // [B]
    const int* __restrict__ source_mask,            // [B] bool->int32
    const int* __restrict__ target_symbol_idx,      // [B]
    const int* __restrict__ target_symbol_mask,     // [B] bool->int32
    const int* __restrict__ target_value_idx,       // [B]
    const int* __restrict__ target_value_mask,      // [B] bool->int32
    const float* __restrict__ map_W1, const float* __restrict__ map_b1,
    const float* __restrict__ map_W2, const float* __restrict__ map_b2,
    const float* __restrict__ step_W1, const float* __restrict__ step_b1,
    const float* __restrict__ step_W2, const float* __restrict__ step_b2,
    float* __restrict__ out)                        // [B*S*V + B*S*S]
{
    const int b    = blockIdx.x >> 1;
    const int head = blockIdx.x & 1;
    const float* W1  = head ? step_W1 : map_W1;
    const float* b1  = head ? step_b1 : map_b1;
    const float* W2  = head ? step_W2 : map_W2;
    const float* b2v = head ? step_b2 : map_b2;

    __shared__ float ev[DD];
    __shared__ float wsum[4];

    const int tid = threadIdx.x;
    for (int i = tid; i < DD; i += 256) ev[i] = evidence[b * DD + i];
    __syncthreads();

    // hidden units j = tid and tid+256; W1 is [D,D] row-major ->
    // at each k, threads read W1[k*D + j] for consecutive j: coalesced.
    float acc = 0.0f;
    #pragma unroll
    for (int jj = 0; jj < DD; jj += 256) {
        const int j = jj + tid;
        float h = b1[j];
        for (int k = 0; k < DD; ++k) {
            h = fmaf(ev[k], W1[k * DD + j], h);
        }
        h = gelu_tanh(h);
        acc = fmaf(h, W2[j], acc);
    }

    // reduce acc over 256 threads: intra-wave (64 lanes) then cross-wave.
    #pragma unroll
    for (int off = 32; off > 0; off >>= 1) acc += __shfl_down(acc, off, 64);
    if ((tid & 63) == 0) wsum[tid >> 6] = acc;
    __syncthreads();

    if (tid == 0) {
        float g = wsum[0] + wsum[1] + wsum[2] + wsum[3] + b2v[0];
        g = 1.0f / (1.0f + expf(-g));    // sigmoid
        const int m  = marker_id[b];
        const bool sm = source_mask[b] != 0;
        if (head == 0) {
            const bool mask = ((m == 1) || (m == 2)) && sm && (target_value_mask[b] != 0);
            if (mask) {
                size_t idx = (size_t)b * SS * VV + (size_t)source_idx[b] * VV
                           + (size_t)target_value_idx[b];
                out[idx] += g;
            }
        } else {
            const bool mask = (m == 3) && sm && (target_symbol_mask[b] != 0);
            if (mask) {
                size_t idx = (size_t)BB * SS * VV + (size_t)b * SS * SS
                           + (size_t)source_idx[b] * SS + (size_t)target_symbol_idx[b];
                out[idx] += g;
            }
        }
    }
}

extern "C" void kernel_launch(void* const* d_in, const int* in_sizes, int n_in,
                              void* d_out, int out_size, void* d_ws, size_t ws_size,
                              hipStream_t stream) {
    const float* map_memory  = (const float*)d_in[0];   // [B,S,V]
    const float* step_memory = (const float*)d_in[1];   // [B,S,S]
    const float* evidence    = (const float*)d_in[2];   // [B,D]
    const int* marker_id     = (const int*)d_in[3];
    const int* source_idx    = (const int*)d_in[4];
    const int* source_mask         = (const int*)d_in[5];
    const int* target_symbol_idx   = (const int*)d_in[6];
    const int* target_symbol_mask  = (const int*)d_in[7];
    const int* target_value_idx    = (const int*)d_in[8];
    const int* target_value_mask   = (const int*)d_in[9];
    const float* map_W1  = (const float*)d_in[10];
    const float* map_b1  = (const float*)d_in[11];
    const float* map_W2  = (const float*)d_in[12];
    const float* map_b2  = (const float*)d_in[13];
    const float* step_W1 = (const float*)d_in[14];
    const float* step_b1 = (const float*)d_in[15];
    const float* step_W2 = (const float*)d_in[16];
    const float* step_b2 = (const float*)d_in[17];

    float* out = (float*)d_out;
    const size_t map_elems  = (size_t)BB * SS * VV;
    const size_t step_elems = (size_t)BB * SS * SS;

    // Bulk pass-through: copy the two memory tensors into the output.
    hipMemcpyAsync(out, map_memory, map_elems * sizeof(float),
                   hipMemcpyDeviceToDevice, stream);
    hipMemcpyAsync(out + map_elems, step_memory, step_elems * sizeof(float),
                   hipMemcpyDeviceToDevice, stream);

    // Gate MLPs + masked single-element scatter-add (after the copies).
    dim3 grid(BB * 2);
    dim3 block(256);
    gate_scatter_kernel<<<grid, block, 0, stream>>>(
        evidence, marker_id, source_idx, source_mask,
        target_symbol_idx, target_symbol_mask,
        target_value_idx, target_value_mask,
        map_W1, map_b1, map_W2, map_b2,
        step_W1, step_b1, step_W2, step_b2,
        out);
}